// Round 1
// baseline (9670.451 us; speedup 1.0000x reference)
//
#include <hip/hip_runtime.h>
#include <cmath>

// VanillaRNN: B=256, T=128, D=1, H=2048, C=10
//   per step: h = tanh(x[:,t]*U^T + h @ W^T + bh)      (U is [H,1] -> U[j])
//   output  : out = h_last @ V^T + bp
// d_out layout: h_last [256*2048] fp32, then output [256*10] fp32.
//
// R1 baseline: fp32 tiled NT-GEMM, 128 sequential step launches.
// h ping-pong: buf0 = d_out h-region, buf1 = d_ws. h_t lives in buf(t&1),
// so h_128 (t even) lands in d_out. buf0 memset to 0 each launch (h0 = 0).

#define B_ 256
#define T_ 128
#define H_ 2048
#define C_ 10

// ---------------- step kernel ----------------
// C[b,j] = sum_k h[b,k] * W[j,k]  (both operands K-contiguous -> NT gemm)
// Tiles: BM=32 (batch), BN=64 (hidden), BK=32. grid (8, 32) = 256 blocks.
__global__ __launch_bounds__(256) void rnn_step(
    const float* __restrict__ h_in,   // [B_, H_]
    float* __restrict__ h_out,        // [B_, H_]
    const float* __restrict__ W,      // [H_, H_]
    const float* __restrict__ U,      // [H_]
    const float* __restrict__ bh,     // [H_]
    const float* __restrict__ x,      // [B_, T_]
    int t)
{
    constexpr int BM = 32, BN = 64, BK = 32;
    // k-major LDS; pads keep rows 16B/8B aligned and dodge pow2 strides:
    // As row = 34 floats (136 B, 8B-aligned for float2 reads)
    // Bs row = 68 floats (272 B, 16B-aligned for float4 reads)
    __shared__ float As[BK][BM + 2];
    __shared__ float Bs[BK][BN + 4];

    const int tid = threadIdx.x;
    const int m0 = blockIdx.x * BM;
    const int n0 = blockIdx.y * BN;

    // compute mapping: tx covers n (4 each), ty covers m (2 each)
    const int tx = tid & 15;   // 0..15 -> n = tx*4
    const int ty = tid >> 4;   // 0..15 -> m = ty*2
    float acc[2][4] = {};

    const int lm = tid >> 3;         // 0..31 (load row)
    const int lk = (tid & 7) * 4;    // 0..28 (load col, float4)

    for (int k0 = 0; k0 < H_; k0 += BK) {
        // A tile: 32x32 floats, 256 thr x float4, store transposed (k-major)
        {
            const float4 a = *(const float4*)&h_in[(m0 + lm) * H_ + k0 + lk];
            As[lk + 0][lm] = a.x; As[lk + 1][lm] = a.y;
            As[lk + 2][lm] = a.z; As[lk + 3][lm] = a.w;
        }
        // B tile: 64x32 floats, 256 thr x 2 float4
        {
            const float4 b0 = *(const float4*)&W[(n0 + lm) * H_ + k0 + lk];
            Bs[lk + 0][lm] = b0.x; Bs[lk + 1][lm] = b0.y;
            Bs[lk + 2][lm] = b0.z; Bs[lk + 3][lm] = b0.w;
            const float4 b1 = *(const float4*)&W[(n0 + 32 + lm) * H_ + k0 + lk];
            Bs[lk + 0][32 + lm] = b1.x; Bs[lk + 1][32 + lm] = b1.y;
            Bs[lk + 2][32 + lm] = b1.z; Bs[lk + 3][32 + lm] = b1.w;
        }
        __syncthreads();
        #pragma unroll
        for (int k = 0; k < BK; ++k) {
            const float2 a = *(const float2*)&As[k][ty * 2];
            const float4 b = *(const float4*)&Bs[k][tx * 4];
            acc[0][0] += a.x * b.x; acc[0][1] += a.x * b.y;
            acc[0][2] += a.x * b.z; acc[0][3] += a.x * b.w;
            acc[1][0] += a.y * b.x; acc[1][1] += a.y * b.y;
            acc[1][2] += a.y * b.z; acc[1][3] += a.y * b.w;
        }
        __syncthreads();
    }

    // epilogue: + x_t[b]*U[j] + bh[j], tanh, vectorized store
    const int m = m0 + ty * 2;
    const int n = n0 + tx * 4;
    const float xb0 = x[(m + 0) * T_ + t];
    const float xb1 = x[(m + 1) * T_ + t];
    const float4 u  = *(const float4*)&U[n];
    const float4 bj = *(const float4*)&bh[n];
    float4 r0, r1;
    r0.x = tanhf(acc[0][0] + xb0 * u.x + bj.x);
    r0.y = tanhf(acc[0][1] + xb0 * u.y + bj.y);
    r0.z = tanhf(acc[0][2] + xb0 * u.z + bj.z);
    r0.w = tanhf(acc[0][3] + xb0 * u.w + bj.w);
    r1.x = tanhf(acc[1][0] + xb1 * u.x + bj.x);
    r1.y = tanhf(acc[1][1] + xb1 * u.y + bj.y);
    r1.z = tanhf(acc[1][2] + xb1 * u.z + bj.z);
    r1.w = tanhf(acc[1][3] + xb1 * u.w + bj.w);
    *(float4*)&h_out[(m + 0) * H_ + n] = r0;
    *(float4*)&h_out[(m + 1) * H_ + n] = r1;
}

// ---------------- output projection ----------------
// out[b,c] = sum_k h[b,k] * V[c,k] + bp[c];  one block per b.
__global__ __launch_bounds__(256) void rnn_out(
    const float* __restrict__ h,    // [B_, H_]
    const float* __restrict__ V,    // [C_, H_]
    const float* __restrict__ bp,   // [C_]
    float* __restrict__ outp)       // [B_, C_]
{
    const int b = blockIdx.x;
    const int tid = threadIdx.x;
    float acc[C_] = {};
    for (int k = tid; k < H_; k += 256) {
        const float hv = h[b * H_ + k];
        #pragma unroll
        for (int c = 0; c < C_; ++c) acc[c] += hv * V[c * H_ + k];
    }
    #pragma unroll
    for (int c = 0; c < C_; ++c) {
        #pragma unroll
        for (int off = 32; off > 0; off >>= 1)
            acc[c] += __shfl_down(acc[c], off, 64);
    }
    __shared__ float partial[4][C_];
    const int wave = tid >> 6, lane = tid & 63;
    if (lane == 0) {
        #pragma unroll
        for (int c = 0; c < C_; ++c) partial[wave][c] = acc[c];
    }
    __syncthreads();
    if (tid < C_) {
        outp[b * C_ + tid] = partial[0][tid] + partial[1][tid]
                           + partial[2][tid] + partial[3][tid] + bp[tid];
    }
}

extern "C" void kernel_launch(void* const* d_in, const int* in_sizes, int n_in,
                              void* d_out, int out_size, void* d_ws, size_t ws_size,
                              hipStream_t stream) {
    const float* x  = (const float*)d_in[0];
    const float* U  = (const float*)d_in[1];
    const float* W  = (const float*)d_in[2];
    const float* V  = (const float*)d_in[3];
    const float* bh = (const float*)d_in[4];
    const float* bp = (const float*)d_in[5];

    float* out   = (float*)d_out;
    float* buf0  = out;                 // h region of d_out [B_*H_]
    float* buf1  = (float*)d_ws;        // ws ping-pong buffer [B_*H_]
    float* outp  = out + (size_t)B_ * H_;

    // h0 = 0 in buf0 (d_out is poisoned 0xAA before every launch)
    hipMemsetAsync(buf0, 0, (size_t)B_ * H_ * sizeof(float), stream);

    dim3 grid(B_ / 32, H_ / 64), block(256);
    for (int t = 0; t < T_; ++t) {
        const float* hin = (t & 1) ? buf1 : buf0;  // h_t lives in buf(t&1)
        float*      hout = (t & 1) ? buf0 : buf1;
        rnn_step<<<grid, block, 0, stream>>>(hin, hout, W, U, bh, x, t);
    }
    // T_=128 even -> h_128 is in buf0 = d_out. Project.
    rnn_out<<<B_, 256, 0, stream>>>(buf0, V, bp, outp);
}

// Round 2
// 2112.545 us; speedup vs baseline: 4.5776x; 4.5776x over previous
//
#include <hip/hip_runtime.h>
#include <cmath>

// VanillaRNN: B=256, T=128, D=1, H=2048, C=10
// step: h = tanh(x[:,t]*U^T + h@W^T + bh); out = h_last@V^T + bp
// R2: fp16 MFMA step GEMM. W split into W_hi+W_lo (fp16 pair -> 22 mantissa
// bits, kills systematic weight-quantization drift); h single fp16 (per-step
// noise only). One NT GEMM per step: C[256,2048] = h[256,2048] * B'[2048,4096]^T
// where B' = [W_hi | W_lo] and A k-index wraps mod 2048 (handled by 2-way
// wave K-split: ks=0 -> W_hi, ks=1 -> W_lo, same A tile).

#define B_ 256
#define T_ 128
#define H_ 2048
#define C_ 10
#define KP 4096  // 2*H_: [W_hi | W_lo]

typedef _Float16 half_t;
typedef _Float16 half8 __attribute__((ext_vector_type(8)));
typedef _Float16 half4v __attribute__((ext_vector_type(4)));
typedef float floatx4 __attribute__((ext_vector_type(4)));

__device__ __forceinline__ void glds16(const void* g, void* l) {
    __builtin_amdgcn_global_load_lds(
        (const __attribute__((address_space(1))) void*)g,
        (__attribute__((address_space(3))) void*)l, 16, 0, 0);
}

// ---------------- W' prep: W fp32 -> [W_hi | W_lo] fp16 ----------------
__global__ __launch_bounds__(256) void prep_w(const float* __restrict__ W,
                                              half_t* __restrict__ Wp) {
    const int idx = blockIdx.x * 256 + threadIdx.x;  // 1M threads x 4 elems
    const int base = idx * 4;
    const int row = base >> 11, col = base & 2047;
    const float4 w = *(const float4*)&W[base];
    half4v hi, lo;
    hi[0] = (half_t)w.x; hi[1] = (half_t)w.y; hi[2] = (half_t)w.z; hi[3] = (half_t)w.w;
    lo[0] = (half_t)(w.x - (float)hi[0]); lo[1] = (half_t)(w.y - (float)hi[1]);
    lo[2] = (half_t)(w.z - (float)hi[2]); lo[3] = (half_t)(w.w - (float)hi[3]);
    *(half4v*)&Wp[(size_t)row * KP + col]      = hi;
    *(half4v*)&Wp[(size_t)row * KP + H_ + col] = lo;
}

// ---------------- MFMA step kernel ----------------
// grid 256 blocks (1/CU), 256 thr = 4 waves: (mw = wave&1) m-half,
// (ks = wave>>1) K-split half (W_hi vs W_lo). Block tile 64x32.
// Wave tile 32x32 = 2x2 mfma_f32_16x16x32_f16. BK=128, double-buffered LDS
// staged via global_load_lds(16B), XOR-swizzled 16B chunks (kc ^ (row&7)).
__global__ __launch_bounds__(256) void rnn_step_mfma(
    const half_t* __restrict__ h_in,   // [B_,H_] fp16
    half_t* __restrict__ h_out,        // [B_,H_] fp16
    const half_t* __restrict__ Wp,     // [H_,KP] fp16
    const float* __restrict__ U,       // [H_]
    const float* __restrict__ bh,      // [H_]
    const float* __restrict__ x,       // [B_,T_]
    int t,
    float* __restrict__ h_f32,         // d_out h region
    int write_f32)
{
    __shared__ half_t Ab[2][64][16][8];     // [buf][m][kc'][8]      32 KB
    __shared__ half_t Bb[2][2][32][16][8];  // [buf][hs][n][kc'][8]  32 KB

    const int tid = threadIdx.x;
    // XCD swizzle: xcd = id&7 owns a contiguous n-range -> W' slice 2MB/XCD L2
    const int id = blockIdx.x;
    const int xcd = id & 7, j = id >> 3;
    const int n0 = (xcd * 8 + (j & 7)) * 32;  // 64 n-tiles of 32
    const int m0 = (j >> 3) * 64;             // 4 m-tiles of 64

    const int wave = tid >> 6, lane = tid & 63;
    const int ks = wave >> 1, mw = wave & 1;
    const int quad = lane >> 4, lq = lane & 15;

    floatx4 acc00 = {}, acc01 = {}, acc10 = {}, acc11 = {};

    auto stageA = [&](int bufi, int kc0) {
#pragma unroll
        for (int it = 0; it < 4; ++it) {
            const int u = it * 256 + tid;                 // LDS 16B-unit index
            const int m = u >> 4, kcp = u & 15;
            const int kc = kcp ^ (m & 7);                 // global chunk for this slot
            glds16(h_in + (size_t)(m0 + m) * H_ + kc0 + kc * 8,
                   (half_t*)Ab + (size_t)bufi * (64 * 16 * 8) + (size_t)u * 8);
        }
    };
    auto stageB = [&](int bufi, int kc0) {
#pragma unroll
        for (int it = 0; it < 4; ++it) {
            const int u = it * 256 + tid;
            const int hs = u >> 9, n = (u >> 4) & 31, kcp = u & 15;
            const int kc = kcp ^ (n & 7);
            glds16(Wp + (size_t)(n0 + n) * KP + hs * H_ + kc0 + kc * 8,
                   (half_t*)Bb + (size_t)bufi * (2 * 32 * 16 * 8) + (size_t)u * 8);
        }
    };
    auto compute = [&](int bufi) {
        const half_t* Ax = (const half_t*)Ab + (size_t)bufi * (64 * 16 * 8);
        const half_t* Bx = (const half_t*)Bb + (size_t)bufi * (2 * 32 * 16 * 8);
        const int mA = mw * 32 + lq;     // (mA&7)==(lq&7); +16 preserves it
#pragma unroll
        for (int kk = 0; kk < 4; ++kk) {
            const int kcs = (kk * 4 + quad) ^ (lq & 7);   // swizzled LDS slot
            const half8 a0 = *(const half8*)(Ax + ((size_t)mA * 16 + kcs) * 8);
            const half8 a1 = *(const half8*)(Ax + ((size_t)(mA + 16) * 16 + kcs) * 8);
            const half8 b0 = *(const half8*)(Bx + ((size_t)(ks * 32 + lq) * 16 + kcs) * 8);
            const half8 b1 = *(const half8*)(Bx + ((size_t)(ks * 32 + lq + 16) * 16 + kcs) * 8);
            acc00 = __builtin_amdgcn_mfma_f32_16x16x32_f16(a0, b0, acc00, 0, 0, 0);
            acc01 = __builtin_amdgcn_mfma_f32_16x16x32_f16(a0, b1, acc01, 0, 0, 0);
            acc10 = __builtin_amdgcn_mfma_f32_16x16x32_f16(a1, b0, acc10, 0, 0, 0);
            acc11 = __builtin_amdgcn_mfma_f32_16x16x32_f16(a1, b1, acc11, 0, 0, 0);
        }
    };

    // prologue + 16-chunk double-buffered K loop (k = 0..2048, BK=128)
    stageA(0, 0); stageB(0, 0);
    __syncthreads();
    int buf = 0;
    for (int c = 0; c < 16; ++c) {
        if (c < 15) { stageA(buf ^ 1, (c + 1) * 128); stageB(buf ^ 1, (c + 1) * 128); }
        compute(buf);
        __syncthreads();  // drains glds (vmcnt) + all waves past buf
        buf ^= 1;
    }

    // K-split reduction: ks=1 waves dump acc into LDS (reuse Ab[0] region)
    float* red = (float*)Ab;  // 2*64*17*4 = 8.7 KB < 16 KB (Ab[0])
    const int rbase = (mw * 64 + lane) * 17;
    if (ks == 1) {
#pragma unroll
        for (int r = 0; r < 4; ++r) {
            red[rbase + 0  + r] = acc00[r];
            red[rbase + 4  + r] = acc01[r];
            red[rbase + 8  + r] = acc10[r];
            red[rbase + 12 + r] = acc11[r];
        }
    }
    __syncthreads();
    if (ks == 0) {
#pragma unroll
        for (int r = 0; r < 4; ++r) {
            acc00[r] += red[rbase + 0  + r];
            acc01[r] += red[rbase + 4  + r];
            acc10[r] += red[rbase + 8  + r];
            acc11[r] += red[rbase + 12 + r];
        }
        // epilogue: +x_t*U +bh, tanh, write fp16 (and fp32 on last step)
        // D layout (16x16): m = quad*4 + reg, n = lq   [m89-verified]
#pragma unroll
        for (int mt = 0; mt < 2; ++mt) {
#pragma unroll
            for (int nt = 0; nt < 2; ++nt) {
                const floatx4 a = mt == 0 ? (nt == 0 ? acc00 : acc01)
                                          : (nt == 0 ? acc10 : acc11);
                const int gn = n0 + nt * 16 + lq;
                const float uv = U[gn], bv = bh[gn];
#pragma unroll
                for (int r = 0; r < 4; ++r) {
                    const int gm = m0 + mw * 32 + mt * 16 + quad * 4 + r;
                    const float pre = a[r] + x[gm * T_ + t] * uv + bv;
                    const float hv = tanhf(pre);
                    h_out[(size_t)gm * H_ + gn] = (half_t)hv;
                    if (write_f32) h_f32[(size_t)gm * H_ + gn] = hv;
                }
            }
        }
    }
}

// ---------------- output projection (reads fp32 h from d_out) ----------------
__global__ __launch_bounds__(256) void rnn_out(
    const float* __restrict__ h, const float* __restrict__ V,
    const float* __restrict__ bp, float* __restrict__ outp) {
    const int b = blockIdx.x;
    const int tid = threadIdx.x;
    float acc[C_] = {};
    for (int k = tid; k < H_; k += 256) {
        const float hv = h[(size_t)b * H_ + k];
#pragma unroll
        for (int c = 0; c < C_; ++c) acc[c] += hv * V[(size_t)c * H_ + k];
    }
#pragma unroll
    for (int c = 0; c < C_; ++c) {
#pragma unroll
        for (int off = 32; off > 0; off >>= 1)
            acc[c] += __shfl_down(acc[c], off, 64);
    }
    __shared__ float partial[4][C_];
    const int wave = tid >> 6, lane = tid & 63;
    if (lane == 0) {
#pragma unroll
        for (int c = 0; c < C_; ++c) partial[wave][c] = acc[c];
    }
    __syncthreads();
    if (tid < C_) {
        outp[b * C_ + tid] = partial[0][tid] + partial[1][tid]
                           + partial[2][tid] + partial[3][tid] + bp[tid];
    }
}

extern "C" void kernel_launch(void* const* d_in, const int* in_sizes, int n_in,
                              void* d_out, int out_size, void* d_ws, size_t ws_size,
                              hipStream_t stream) {
    const float* x  = (const float*)d_in[0];
    const float* U  = (const float*)d_in[1];
    const float* W  = (const float*)d_in[2];
    const float* V  = (const float*)d_in[3];
    const float* bh = (const float*)d_in[4];
    const float* bp = (const float*)d_in[5];

    float* out_h = (float*)d_out;                      // [B_*H_] fp32 h_last
    float* outp  = out_h + (size_t)B_ * H_;            // [B_*C_]

    half_t* Wp = (half_t*)d_ws;                                    // 16 MB
    half_t* hA = (half_t*)((char*)d_ws + (size_t)16 * 1024 * 1024); // 1 MB
    half_t* hB = hA + (size_t)B_ * H_;                              // 1 MB

    hipMemsetAsync(hA, 0, (size_t)B_ * H_ * sizeof(half_t), stream);  // h0 = 0
    prep_w<<<dim3((H_ * H_ / 4) / 256), dim3(256), 0, stream>>>(W, Wp);

    for (int t = 0; t < T_; ++t) {
        const half_t* hin = (t & 1) ? hB : hA;
        half_t*      hout = (t & 1) ? hA : hB;
        rnn_step_mfma<<<dim3(256), dim3(256), 0, stream>>>(
            hin, hout, Wp, U, bh, x, t, out_h, (t == T_ - 1) ? 1 : 0);
    }
    rnn_out<<<dim3(B_), dim3(256), 0, stream>>>(out_h, V, bp, outp);
}